// Round 18
// baseline (157.523 us; speedup 1.0000x reference)
//
#include <hip/hip_runtime.h>
#include <hip/hip_bf16.h>
#include <stdint.h>

#define NN 50000
#define EE 500000
#define NSCAT 487   // scatter blocks in the fused grid (97*5 + 2)

typedef __attribute__((ext_vector_type(8))) short short8;
typedef __attribute__((ext_vector_type(4))) float f32x4;
typedef __attribute__((ext_vector_type(2))) float f32x2;
typedef __attribute__((ext_vector_type(4))) unsigned short u16x4;
typedef __attribute__((ext_vector_type(4))) unsigned int u32x4;

__device__ __forceinline__ unsigned short f2bf(float f) {
  union { float f; uint32_t u; } v; v.f = f;
  uint32_t u = v.u;
  return (unsigned short)((u + 0x7FFFu + ((u >> 16) & 1u)) >> 16);
}

__device__ __forceinline__ f32x4 bf4(const unsigned short* p) {
  u16x4 v = *(const u16x4*)p;
  f32x4 r;
  #pragma unroll
  for (int j = 0; j < 4; ++j) {
    union { uint32_t u; float f; } c; c.u = ((uint32_t)(unsigned short)v[j]) << 16; r[j] = c.f;
  }
  return r;
}

// decode 4 OCP e4m3 fp8 packed in a u32 -> 4 floats
__device__ __forceinline__ f32x4 fp8x4(uint32_t v) {
  f32x2 lo = __builtin_amdgcn_cvt_pk_f32_fp8(v, false);
  f32x2 hi = __builtin_amdgcn_cvt_pk_f32_fp8(v, true);
  f32x4 r; r[0] = lo[0]; r[1] = lo[1]; r[2] = hi[0]; r[3] = hi[1];
  return r;
}

// ---- combined W in MFMA-FRAGMENT order (+ zero cnt ints in extra blocks).
__global__ void k_prep0(const float* __restrict__ Wi, const float* __restrict__ Wt,
                        unsigned short* __restrict__ wtf, int* __restrict__ cnt) {
  const int b = blockIdx.x;
  if (b >= 1024) {   // zero 800,000 counter ints (3.2 MB)
    const int idx = (b - 1024) * 2048 + threadIdx.x * 8;
    if (idx < 800000) {
      *(u32x4*)(cnt + idx) = (u32x4){0u, 0u, 0u, 0u};
      *(u32x4*)(cnt + idx + 4) = (u32x4){0u, 0u, 0u, 0u};
    }
    return;
  }
  const int i = b * 256 + threadIdx.x;
  const int o = i >> 8, k = i & 255;
  const float* W = (o < 512) ? Wi : Wt;
  const int oo = o & 511;
  const float v = (oo < 256) ? (W[oo * 512 + k] - W[oo * 512 + 256 + k])
                             : W[(oo - 256) * 512 + 256 + k];
  const int nt = o >> 8, wcv = (o >> 6) & 3, fn = (o >> 4) & 3, fl = o & 15;
  const int kt = k >> 5, fh = (k >> 3) & 3, j = k & 7;
  const int frag = (nt * 8 + kt) * 16 + wcv * 4 + fn;
  wtf[(size_t)frag * 512 + (fh * 16 + fl) * 8 + j] = f2bf(v);
}

// LDS swizzles
#define SWZA(row, c) ((row) * 256 + ((((c) ^ ((row) & 7))) << 3))
#define SCR(row, c)  ((row) * 256 + ((((c) ^ ((row) & 7))) << 3))
#define SCR8(row, colb) ((row) * 256 + ((colb) ^ ((((row) >> 2) & 3) << 4)))

__device__ __forceinline__ void scat_edge(const int* __restrict__ e, int* __restrict__ cnt,
                                          unsigned short* __restrict__ so, int idx, int rep) {
  const int d = e[EE + idx];
  const int slot = atomicAdd(&cnt[rep * NN + d], 1);
  if (slot < 16) so[d * 128 + rep * 16 + slot] = (unsigned short)e[idx];
}

// ---- FUSED (block-level roles): per 13 blocks, 8 = gemm panel, 5 = scatter.
// Gemm role: r15 structure + EXPLICIT B register double-buffer in the
// barrier-free K-loop (load kt+1 while kt's MFMAs run) at unchanged
// __launch_bounds__(256,3). Scatter role: grid-stride, 8-way repl. counters.
__launch_bounds__(256, 3)
__global__ void k_fused(const float* __restrict__ x, const unsigned short* __restrict__ wtf,
                        const float* __restrict__ b_int, const float* __restrict__ b_tp,
                        unsigned short* __restrict__ YA, unsigned char* __restrict__ Bi,
                        unsigned char* __restrict__ Bt, int M,
                        const int* __restrict__ ei, const int* __restrict__ et,
                        int* __restrict__ cnt_i, int* __restrict__ cnt_t,
                        unsigned short* __restrict__ so_i, unsigned short* __restrict__ so_t) {
  __shared__ unsigned short lA[64 * 256];    // 32 KB
  __shared__ unsigned short scr[32 * 256];   // 16 KB epilogue scratch
  const int tid = threadIdx.x;
  const int g13 = blockIdx.x / 13, r13 = blockIdx.x % 13;

  if (r13 >= 8) {
    // ================= scatter role =================
    const int sid = g13 * 5 + (r13 - 8);     // 0..486
    const int rep = blockIdx.x & 7;          // XCD-aligned replica
    for (int idx = sid * 256 + tid; idx < EE; idx += NSCAT * 256)
      scat_edge(ei, cnt_i, so_i, idx, rep);
    for (int idx = sid * 256 + tid; idx < EE; idx += NSCAT * 256)
      scat_edge(et, cnt_t, so_t, idx, rep);
    return;
  }

  // ================= gemm role =================
  const int gid = g13 * 8 + r13;             // 0..783
  if (gid >= 782) return;
  const int lane = tid & 63;
  const int wc   = tid >> 6;                 // 4 waves = 4 col-slices of 64
  const int row0 = gid * 64;
  const int fl = lane & 15, fh = lane >> 4;

  // B fragment loader: s = nt*8+kt global step (0..31)
  short8 bq[2][4];
  #define LOADB(s, b) { \
    const unsigned short* wb = wtf + ((size_t)((s) * 16 + wc * 4)) * 512 + lane * 8; \
    _Pragma("unroll") \
    for (int fn = 0; fn < 4; ++fn) bq[b][fn] = *(const short8*)(wb + fn * 512); }

  LOADB(0, 0);                               // in flight under the A-stage

  // ---- stage A panel: 64 rows x 256 cols f32 -> bf16 in LDS (2048 chunks)
  #pragma unroll
  for (int j = 0; j < 8; ++j) {
    const int cidx = j * 256 + tid;
    const int arow = cidx >> 5, c = cidx & 31;
    const int gr = min(row0 + arow, M - 1);
    const float* p = x + (size_t)gr * 256 + c * 8;
    const f32x4 lo = *(const f32x4*)p;
    const f32x4 hi = *(const f32x4*)(p + 4);
    short8 v;
    #pragma unroll
    for (int q = 0; q < 4; ++q) { v[q] = (short)f2bf(lo[q]); v[q + 4] = (short)f2bf(hi[q]); }
    *(short8*)(&lA[SWZA(arow, c)]) = v;
  }
  __syncthreads();

  for (int nt = 0; nt < 4; ++nt) {
    f32x4 acc[4][4];
    #pragma unroll
    for (int i = 0; i < 4; ++i)
      #pragma unroll
      for (int j = 0; j < 4; ++j) acc[i][j] = (f32x4){0.f, 0.f, 0.f, 0.f};

    // ---- barrier-free K loop, B double-buffered in registers
    #pragma unroll
    for (int kt = 0; kt < 8; ++kt) {
      const int s = nt * 8 + kt;
      if (s < 31) LOADB(s + 1, (kt & 1) ^ 1);   // prefetch next step
      short8 af[4];
      #pragma unroll
      for (int fm = 0; fm < 4; ++fm)
        af[fm] = *(const short8*)(&lA[SWZA(fm * 16 + fl, kt * 4 + fh)]);
      #pragma unroll
      for (int fm = 0; fm < 4; ++fm)
        #pragma unroll
        for (int fn = 0; fn < 4; ++fn)
          acc[fm][fn] = __builtin_amdgcn_mfma_f32_16x16x32_bf16(af[fm], bq[kt & 1][fn], acc[fm][fn], 0, 0, 0);
    }

    // acc[fm][fn][r]: row = fm*16 + fh*4 + r (0..63), col = wc*64 + fn*16 + fl (0..255)
    if ((nt & 1) == 0) {
      // ---- bf16 A-half epilogue (+bias): 2 phases x 32 rows through scr
      const float* bias = (nt == 0) ? b_int : b_tp;
      const int ycol0 = (nt == 0) ? 0 : 256;
      float bv[4];
      #pragma unroll
      for (int fn = 0; fn < 4; ++fn)
        bv[fn] = bias[wc * 64 + fn * 16 + fl];
      #pragma unroll
      for (int p = 0; p < 2; ++p) {
        __syncthreads();                     // scratch free
        #pragma unroll
        for (int f2 = 0; f2 < 2; ++f2) {
          const int fm = p * 2 + f2;
          #pragma unroll
          for (int fn = 0; fn < 4; ++fn) {
            const int col = wc * 64 + fn * 16 + fl;
            #pragma unroll
            for (int r = 0; r < 4; ++r) {
              const int lr = f2 * 16 + fh * 4 + r;
              scr[SCR(lr, col >> 3) + (col & 7)] = f2bf(acc[fm][fn][r] + bv[fn]);
            }
          }
        }
        __syncthreads();                     // scratch ready
        const int tr = tid >> 3;             // 32 rows, 8 threads/row
        const int grow = row0 + p * 32 + tr;
        if (grow < M) {
          #pragma unroll
          for (int j = 0; j < 4; ++j) {
            const int c = (tid & 7) + 8 * j;
            const short8 v = *(const short8*)(&scr[SCR(tr, c)]);
            *(short8*)(&YA[(size_t)grow * 512 + ycol0 + c * 8]) = v;
          }
        }
      }
    } else {
      // ---- fp8 B-half epilogue: whole 64x256 tile through scr (16 KB)
      unsigned char* dst = (nt == 1) ? Bi : Bt;
      unsigned char* s8 = (unsigned char*)scr;
      __syncthreads();                       // scratch free
      #pragma unroll
      for (int fm = 0; fm < 4; ++fm) {
        const int rbase = fm * 16 + fh * 4;
        #pragma unroll
        for (int fn = 0; fn < 4; ++fn) {
          const int col = wc * 64 + fn * 16 + fl;
          const uint32_t p01 = __builtin_amdgcn_cvt_pk_fp8_f32(acc[fm][fn][0], acc[fm][fn][1], 0u, false);
          const uint32_t p23 = __builtin_amdgcn_cvt_pk_fp8_f32(acc[fm][fn][2], acc[fm][fn][3], 0u, false);
          s8[SCR8(rbase + 0, col)] = (unsigned char)(p01 & 0xFF);
          s8[SCR8(rbase + 1, col)] = (unsigned char)((p01 >> 8) & 0xFF);
          s8[SCR8(rbase + 2, col)] = (unsigned char)(p23 & 0xFF);
          s8[SCR8(rbase + 3, col)] = (unsigned char)((p23 >> 8) & 0xFF);
        }
      }
      __syncthreads();                       // scratch ready
      const int tr = tid >> 2;               // 64 rows, 4 threads/row
      const int grow = row0 + tr;
      if (grow < M) {
        #pragma unroll
        for (int j = 0; j < 4; ++j) {
          const int c16 = ((tid & 3) + 4 * j) * 16;
          u32x4 w;
          #pragma unroll
          for (int d = 0; d < 4; ++d)
            w[d] = *(const uint32_t*)(s8 + SCR8(tr, c16) + d * 4);
          *(u32x4*)(dst + (size_t)grow * 256 + c16) = w;
        }
      }
      __syncthreads();                       // readers done before next nt writes
    }
  }
  #undef LOADB
}

// ---- fused aggregate: one wave per dst node (unchanged)
__global__ void k_agg2(const unsigned short* __restrict__ YA,
                       const uint32_t* __restrict__ Bi, const uint32_t* __restrict__ Bt,
                       const int* __restrict__ cnt_i, const int* __restrict__ cnt_t,
                       const uint32_t* __restrict__ so_i, const uint32_t* __restrict__ so_t,
                       float* __restrict__ out) {
  const int node = blockIdx.x * 4 + (threadIdx.x >> 6);
  if (node >= NN) return;
  const int lane = threadIdx.x & 63;
  const int c4 = lane << 2;

  const uint32_t bw_i = so_i[(size_t)node * 64 + lane];
  const uint32_t bw_t = so_t[(size_t)node * 64 + lane];
  int ncnt = 0;
  if (lane < 16) {
    const int* cp = (lane < 8) ? cnt_i : cnt_t;
    ncnt = cp[(lane & 7) * NN + node];
  }
  const f32x4 ai = bf4(YA + (size_t)node * 512 + c4);
  const f32x4 at = bf4(YA + (size_t)node * 512 + 256 + c4);

  f32x4 mx = (f32x4){0.f, 0.f, 0.f, 0.f};
  f32x4 sm = (f32x4){0.f, 0.f, 0.f, 0.f};

  #pragma unroll
  for (int r = 0; r < 8; ++r) {
    const int n = min(__shfl(ncnt, r), 16);
    int k = 0;
    for (; k + 2 <= n; k += 2) {
      const uint32_t w = (uint32_t)__shfl((int)bw_i, r * 8 + (k >> 1));
      const int s0 = w & 0xFFFF, s1 = w >> 16;
      const f32x4 b0 = fp8x4(Bi[(size_t)s0 * 64 + lane]);
      const f32x4 b1 = fp8x4(Bi[(size_t)s1 * 64 + lane]);
      #pragma unroll
      for (int j = 0; j < 4; ++j)
        mx[j] = fmaxf(mx[j], fmaxf(fmaxf(ai[j] + b0[j], 0.0f), fmaxf(ai[j] + b1[j], 0.0f)));
    }
    if (k < n) {
      const uint32_t w = (uint32_t)__shfl((int)bw_i, r * 8 + (k >> 1));
      const int s0 = w & 0xFFFF;
      const f32x4 b0 = fp8x4(Bi[(size_t)s0 * 64 + lane]);
      #pragma unroll
      for (int j = 0; j < 4; ++j) mx[j] = fmaxf(mx[j], fmaxf(ai[j] + b0[j], 0.0f));
    }
  }

  #pragma unroll
  for (int r = 0; r < 8; ++r) {
    const int n = min(__shfl(ncnt, r + 8), 16);
    int k = 0;
    for (; k + 2 <= n; k += 2) {
      const uint32_t w = (uint32_t)__shfl((int)bw_t, r * 8 + (k >> 1));
      const int s0 = w & 0xFFFF, s1 = w >> 16;
      const f32x4 b0 = fp8x4(Bt[(size_t)s0 * 64 + lane]);
      const f32x4 b1 = fp8x4(Bt[(size_t)s1 * 64 + lane]);
      #pragma unroll
      for (int j = 0; j < 4; ++j)
        sm[j] += fmaxf(at[j] + b0[j], 0.0f) + fmaxf(at[j] + b1[j], 0.0f);
    }
    if (k < n) {
      const uint32_t w = (uint32_t)__shfl((int)bw_t, r * 8 + (k >> 1));
      const int s0 = w & 0xFFFF;
      const f32x4 b0 = fp8x4(Bt[(size_t)s0 * 64 + lane]);
      #pragma unroll
      for (int j = 0; j < 4; ++j) sm[j] += fmaxf(at[j] + b0[j], 0.0f);
    }
  }

  f32x4 o;
  #pragma unroll
  for (int j = 0; j < 4; ++j) o[j] = mx[j] + sm[j];
  *(f32x4*)(out + (size_t)node * 256 + c4) = o;
}

extern "C" void kernel_launch(void* const* d_in, const int* in_sizes, int n_in,
                              void* d_out, int out_size, void* d_ws, size_t ws_size,
                              hipStream_t stream) {
  const float* x     = (const float*)d_in[0];
  const int*   e_tp  = (const int*)d_in[1];
  const int*   e_int = (const int*)d_in[2];
  const float* W_tp  = (const float*)d_in[3];
  const float* b_tp  = (const float*)d_in[4];
  const float* W_int = (const float*)d_in[5];
  const float* b_int = (const float*)d_in[6];
  float* out = (float*)d_out;

  char* w = (char*)d_ws;
  unsigned short* YA = (unsigned short*)w;               // 51,200,000 B
  unsigned char*  Bi = (unsigned char*)(w + 51200000);   // 12,800,000
  unsigned char*  Bt = (unsigned char*)(w + 64000000);   // 12,800,000
  int* cnt_i = (int*)(w + 76800000);                     //  1,600,000 (8 x 50000)
  int* cnt_t = (int*)(w + 78400000);                     //  1,600,000 (contiguous)
  unsigned short* so_i = (unsigned short*)(w + 80000000);  // 12,800,000 (u16, 128/node)
  unsigned short* so_t = (unsigned short*)(w + 92800000);  // 12,800,000
  unsigned short* wtf = (unsigned short*)(w + 105600000); //    524,288  -> 106.1 MB total

  k_prep0<<<1024 + 391, 256, 0, stream>>>(W_int, W_tp, wtf, cnt_i);
  // 1271 blocks = 97*13 + 10: per 13 -> 8 gemm + 5 scatter (gemm 782, scatter 487)
  k_fused<<<dim3(1271), dim3(256), 0, stream>>>(x, wtf, b_int, b_tp, YA, Bi, Bt, NN,
                                                e_int, e_tp, cnt_i, cnt_t, so_i, so_t);
  k_agg2<<<12500, 256, 0, stream>>>(YA, (const uint32_t*)Bi, (const uint32_t*)Bt,
                                    cnt_i, cnt_t, (const uint32_t*)so_i, (const uint32_t*)so_t, out);
}

// Round 19
// 139.938 us; speedup vs baseline: 1.1257x; 1.1257x over previous
//
#include <hip/hip_runtime.h>
#include <hip/hip_bf16.h>
#include <stdint.h>

#define NN 50000
#define EE 500000
#define NSCAT 487   // scatter blocks in the fused grid (97*5 + 2)

typedef __attribute__((ext_vector_type(8))) short short8;
typedef __attribute__((ext_vector_type(4))) float f32x4;
typedef __attribute__((ext_vector_type(2))) float f32x2;
typedef __attribute__((ext_vector_type(4))) unsigned short u16x4;
typedef __attribute__((ext_vector_type(4))) unsigned int u32x4;

__device__ __forceinline__ unsigned short f2bf(float f) {
  union { float f; uint32_t u; } v; v.f = f;
  uint32_t u = v.u;
  return (unsigned short)((u + 0x7FFFu + ((u >> 16) & 1u)) >> 16);
}

__device__ __forceinline__ f32x4 bf4(const unsigned short* p) {
  u16x4 v = *(const u16x4*)p;
  f32x4 r;
  #pragma unroll
  for (int j = 0; j < 4; ++j) {
    union { uint32_t u; float f; } c; c.u = ((uint32_t)(unsigned short)v[j]) << 16; r[j] = c.f;
  }
  return r;
}

// decode 4 OCP e4m3 fp8 packed in a u32 -> 4 floats
__device__ __forceinline__ f32x4 fp8x4(uint32_t v) {
  f32x2 lo = __builtin_amdgcn_cvt_pk_f32_fp8(v, false);
  f32x2 hi = __builtin_amdgcn_cvt_pk_f32_fp8(v, true);
  f32x4 r; r[0] = lo[0]; r[1] = lo[1]; r[2] = hi[0]; r[3] = hi[1];
  return r;
}

// ---- combined W in MFMA-FRAGMENT order (+ zero cnt ints in extra blocks).
__global__ void k_prep0(const float* __restrict__ Wi, const float* __restrict__ Wt,
                        unsigned short* __restrict__ wtf, int* __restrict__ cnt) {
  const int b = blockIdx.x;
  if (b >= 1024) {   // zero 800,000 counter ints (3.2 MB)
    const int idx = (b - 1024) * 2048 + threadIdx.x * 8;
    if (idx < 800000) {
      *(u32x4*)(cnt + idx) = (u32x4){0u, 0u, 0u, 0u};
      *(u32x4*)(cnt + idx + 4) = (u32x4){0u, 0u, 0u, 0u};
    }
    return;
  }
  const int i = b * 256 + threadIdx.x;
  const int o = i >> 8, k = i & 255;
  const float* W = (o < 512) ? Wi : Wt;
  const int oo = o & 511;
  const float v = (oo < 256) ? (W[oo * 512 + k] - W[oo * 512 + 256 + k])
                             : W[(oo - 256) * 512 + 256 + k];
  const int nt = o >> 8, wcv = (o >> 6) & 3, fn = (o >> 4) & 3, fl = o & 15;
  const int kt = k >> 5, fh = (k >> 3) & 3, j = k & 7;
  const int frag = (nt * 8 + kt) * 16 + wcv * 4 + fn;
  wtf[(size_t)frag * 512 + (fh * 16 + fl) * 8 + j] = f2bf(v);
}

// LDS swizzles
#define SWZA(row, c) ((row) * 256 + ((((c) ^ ((row) & 7))) << 3))
// bf16 epilogue scratch, 16 rows x 256 elems (8 KB)
#define SCR16(row, c) ((row) * 256 + ((((c) ^ ((row) & 7))) << 3))
// fp8 epilogue scratch, 32 rows x 256 bytes (8 KB)
#define SCR8(row, colb) ((row) * 256 + ((colb) ^ ((((row) >> 2) & 3) << 4)))

__device__ __forceinline__ void scat_edge(const int* __restrict__ e, int* __restrict__ cnt,
                                          unsigned short* __restrict__ so, int idx, int rep) {
  const int d = e[EE + idx];
  const int slot = atomicAdd(&cnt[rep * NN + d], 1);
  if (slot < 16) so[d * 128 + rep * 16 + slot] = (unsigned short)e[idx];
}

// ---- FUSED (block-level roles): per 13 blocks, 8 = gemm panel, 5 = scatter.
// Gemm role: r15 structure, UNCHANGED (256,3) regalloc; only the epilogue
// scratch shrinks 16->8 KB so total LDS = 40 KB -> 4 blocks/CU co-resident.
// Scatter role: grid-stride, 8-way replicated counters.
__launch_bounds__(256, 3)
__global__ void k_fused(const float* __restrict__ x, const unsigned short* __restrict__ wtf,
                        const float* __restrict__ b_int, const float* __restrict__ b_tp,
                        unsigned short* __restrict__ YA, unsigned char* __restrict__ Bi,
                        unsigned char* __restrict__ Bt, int M,
                        const int* __restrict__ ei, const int* __restrict__ et,
                        int* __restrict__ cnt_i, int* __restrict__ cnt_t,
                        unsigned short* __restrict__ so_i, unsigned short* __restrict__ so_t) {
  __shared__ unsigned short lA[64 * 256];    // 32 KB
  __shared__ unsigned short scr[16 * 256];   // 8 KB epilogue scratch -> LDS 40 KB
  const int tid = threadIdx.x;
  const int g13 = blockIdx.x / 13, r13 = blockIdx.x % 13;

  if (r13 >= 8) {
    // ================= scatter role =================
    const int sid = g13 * 5 + (r13 - 8);     // 0..486
    const int rep = blockIdx.x & 7;          // XCD-aligned replica
    for (int idx = sid * 256 + tid; idx < EE; idx += NSCAT * 256)
      scat_edge(ei, cnt_i, so_i, idx, rep);
    for (int idx = sid * 256 + tid; idx < EE; idx += NSCAT * 256)
      scat_edge(et, cnt_t, so_t, idx, rep);
    return;
  }

  // ================= gemm role =================
  const int gid = g13 * 8 + r13;             // 0..783
  if (gid >= 782) return;
  const int lane = tid & 63;
  const int wc   = tid >> 6;                 // 4 waves = 4 col-slices of 64
  const int row0 = gid * 64;
  const int fl = lane & 15, fh = lane >> 4;

  // ---- stage A panel: 64 rows x 256 cols f32 -> bf16 in LDS (2048 chunks)
  #pragma unroll
  for (int j = 0; j < 8; ++j) {
    const int cidx = j * 256 + tid;
    const int arow = cidx >> 5, c = cidx & 31;
    const int gr = min(row0 + arow, M - 1);
    const float* p = x + (size_t)gr * 256 + c * 8;
    const f32x4 lo = *(const f32x4*)p;
    const f32x4 hi = *(const f32x4*)(p + 4);
    short8 v;
    #pragma unroll
    for (int q = 0; q < 4; ++q) { v[q] = (short)f2bf(lo[q]); v[q + 4] = (short)f2bf(hi[q]); }
    *(short8*)(&lA[SWZA(arow, c)]) = v;
  }
  __syncthreads();

  for (int nt = 0; nt < 4; ++nt) {
    f32x4 acc[4][4];
    #pragma unroll
    for (int i = 0; i < 4; ++i)
      #pragma unroll
      for (int j = 0; j < 4; ++j) acc[i][j] = (f32x4){0.f, 0.f, 0.f, 0.f};

    // ---- barrier-free K loop: A from LDS, B coalesced from wtf (L2-hot)
    #pragma unroll
    for (int kt = 0; kt < 8; ++kt) {
      const unsigned short* wbase = wtf + ((size_t)((nt * 8 + kt) * 16 + wc * 4)) * 512 + lane * 8;
      short8 af[4], bq[4];
      #pragma unroll
      for (int fn = 0; fn < 4; ++fn)
        bq[fn] = *(const short8*)(wbase + fn * 512);
      #pragma unroll
      for (int fm = 0; fm < 4; ++fm)
        af[fm] = *(const short8*)(&lA[SWZA(fm * 16 + fl, kt * 4 + fh)]);
      #pragma unroll
      for (int fm = 0; fm < 4; ++fm)
        #pragma unroll
        for (int fn = 0; fn < 4; ++fn)
          acc[fm][fn] = __builtin_amdgcn_mfma_f32_16x16x32_bf16(af[fm], bq[fn], acc[fm][fn], 0, 0, 0);
    }

    // acc[fm][fn][r]: row = fm*16 + fh*4 + r (0..63), col = wc*64 + fn*16 + fl (0..255)
    if ((nt & 1) == 0) {
      // ---- bf16 A-half epilogue (+bias): 4 phases x 16 rows through scr
      const float* bias = (nt == 0) ? b_int : b_tp;
      const int ycol0 = (nt == 0) ? 0 : 256;
      float bv[4];
      #pragma unroll
      for (int fn = 0; fn < 4; ++fn)
        bv[fn] = bias[wc * 64 + fn * 16 + fl];
      #pragma unroll
      for (int p = 0; p < 4; ++p) {
        __syncthreads();                     // scratch free
        #pragma unroll
        for (int fn = 0; fn < 4; ++fn) {
          const int col = wc * 64 + fn * 16 + fl;
          #pragma unroll
          for (int r = 0; r < 4; ++r) {
            const int lr = fh * 4 + r;       // 0..15
            scr[SCR16(lr, col >> 3) + (col & 7)] = f2bf(acc[p][fn][r] + bv[fn]);
          }
        }
        __syncthreads();                     // scratch ready
        const int tr = tid >> 4;             // 16 rows, 16 threads/row
        const int grow = row0 + p * 16 + tr;
        if (grow < M) {
          #pragma unroll
          for (int j = 0; j < 2; ++j) {
            const int c = (tid & 15) + 16 * j;
            const short8 v = *(const short8*)(&scr[SCR16(tr, c)]);
            *(short8*)(&YA[(size_t)grow * 512 + ycol0 + c * 8]) = v;
          }
        }
      }
    } else {
      // ---- fp8 B-half epilogue: 2 phases x 32 rows through scr
      unsigned char* dst = (nt == 1) ? Bi : Bt;
      unsigned char* s8 = (unsigned char*)scr;
      #pragma unroll
      for (int p = 0; p < 2; ++p) {
        __syncthreads();                     // scratch free
        #pragma unroll
        for (int f2 = 0; f2 < 2; ++f2) {
          const int fm = p * 2 + f2;
          const int rbase = f2 * 16 + fh * 4;  // 0..31
          #pragma unroll
          for (int fn = 0; fn < 4; ++fn) {
            const int col = wc * 64 + fn * 16 + fl;
            const uint32_t p01 = __builtin_amdgcn_cvt_pk_fp8_f32(acc[fm][fn][0], acc[fm][fn][1], 0u, false);
            const uint32_t p23 = __builtin_amdgcn_cvt_pk_fp8_f32(acc[fm][fn][2], acc[fm][fn][3], 0u, false);
            s8[SCR8(rbase + 0, col)] = (unsigned char)(p01 & 0xFF);
            s8[SCR8(rbase + 1, col)] = (unsigned char)((p01 >> 8) & 0xFF);
            s8[SCR8(rbase + 2, col)] = (unsigned char)(p23 & 0xFF);
            s8[SCR8(rbase + 3, col)] = (unsigned char)((p23 >> 8) & 0xFF);
          }
        }
        __syncthreads();                     // scratch ready
        const int tr = tid >> 3;             // 32 rows, 8 threads/row
        const int grow = row0 + p * 32 + tr;
        if (grow < M) {
          #pragma unroll
          for (int j = 0; j < 2; ++j) {
            const int c16 = ((tid & 7) * 2 + j) * 16;
            u32x4 w;
            #pragma unroll
            for (int d = 0; d < 4; ++d)
              w[d] = *(const uint32_t*)(s8 + SCR8(tr, c16) + d * 4);
            *(u32x4*)(dst + (size_t)grow * 256 + c16) = w;
          }
        }
      }
      if (nt == 1) __syncthreads();          // scr safe before nt=2 epilogue
    }
  }
}

// ---- fused aggregate: one wave per dst node (unchanged)
__global__ void k_agg2(const unsigned short* __restrict__ YA,
                       const uint32_t* __restrict__ Bi, const uint32_t* __restrict__ Bt,
                       const int* __restrict__ cnt_i, const int* __restrict__ cnt_t,
                       const uint32_t* __restrict__ so_i, const uint32_t* __restrict__ so_t,
                       float* __restrict__ out) {
  const int node = blockIdx.x * 4 + (threadIdx.x >> 6);
  if (node >= NN) return;
  const int lane = threadIdx.x & 63;
  const int c4 = lane << 2;

  const uint32_t bw_i = so_i[(size_t)node * 64 + lane];
  const uint32_t bw_t = so_t[(size_t)node * 64 + lane];
  int ncnt = 0;
  if (lane < 16) {
    const int* cp = (lane < 8) ? cnt_i : cnt_t;
    ncnt = cp[(lane & 7) * NN + node];
  }
  const f32x4 ai = bf4(YA + (size_t)node * 512 + c4);
  const f32x4 at = bf4(YA + (size_t)node * 512 + 256 + c4);

  f32x4 mx = (f32x4){0.f, 0.f, 0.f, 0.f};
  f32x4 sm = (f32x4){0.f, 0.f, 0.f, 0.f};

  #pragma unroll
  for (int r = 0; r < 8; ++r) {
    const int n = min(__shfl(ncnt, r), 16);
    int k = 0;
    for (; k + 2 <= n; k += 2) {
      const uint32_t w = (uint32_t)__shfl((int)bw_i, r * 8 + (k >> 1));
      const int s0 = w & 0xFFFF, s1 = w >> 16;
      const f32x4 b0 = fp8x4(Bi[(size_t)s0 * 64 + lane]);
      const f32x4 b1 = fp8x4(Bi[(size_t)s1 * 64 + lane]);
      #pragma unroll
      for (int j = 0; j < 4; ++j)
        mx[j] = fmaxf(mx[j], fmaxf(fmaxf(ai[j] + b0[j], 0.0f), fmaxf(ai[j] + b1[j], 0.0f)));
    }
    if (k < n) {
      const uint32_t w = (uint32_t)__shfl((int)bw_i, r * 8 + (k >> 1));
      const int s0 = w & 0xFFFF;
      const f32x4 b0 = fp8x4(Bi[(size_t)s0 * 64 + lane]);
      #pragma unroll
      for (int j = 0; j < 4; ++j) mx[j] = fmaxf(mx[j], fmaxf(ai[j] + b0[j], 0.0f));
    }
  }

  #pragma unroll
  for (int r = 0; r < 8; ++r) {
    const int n = min(__shfl(ncnt, r + 8), 16);
    int k = 0;
    for (; k + 2 <= n; k += 2) {
      const uint32_t w = (uint32_t)__shfl((int)bw_t, r * 8 + (k >> 1));
      const int s0 = w & 0xFFFF, s1 = w >> 16;
      const f32x4 b0 = fp8x4(Bt[(size_t)s0 * 64 + lane]);
      const f32x4 b1 = fp8x4(Bt[(size_t)s1 * 64 + lane]);
      #pragma unroll
      for (int j = 0; j < 4; ++j)
        sm[j] += fmaxf(at[j] + b0[j], 0.0f) + fmaxf(at[j] + b1[j], 0.0f);
    }
    if (k < n) {
      const uint32_t w = (uint32_t)__shfl((int)bw_t, r * 8 + (k >> 1));
      const int s0 = w & 0xFFFF;
      const f32x4 b0 = fp8x4(Bt[(size_t)s0 * 64 + lane]);
      #pragma unroll
      for (int j = 0; j < 4; ++j) sm[j] += fmaxf(at[j] + b0[j], 0.0f);
    }
  }

  f32x4 o;
  #pragma unroll
  for (int j = 0; j < 4; ++j) o[j] = mx[j] + sm[j];
  *(f32x4*)(out + (size_t)node * 256 + c4) = o;
}

extern "C" void kernel_launch(void* const* d_in, const int* in_sizes, int n_in,
                              void* d_out, int out_size, void* d_ws, size_t ws_size,
                              hipStream_t stream) {
  const float* x     = (const float*)d_in[0];
  const int*   e_tp  = (const int*)d_in[1];
  const int*   e_int = (const int*)d_in[2];
  const float* W_tp  = (const float*)d_in[3];
  const float* b_tp  = (const float*)d_in[4];
  const float* W_int = (const float*)d_in[5];
  const float* b_int = (const float*)d_in[6];
  float* out = (float*)d_out;

  char* w = (char*)d_ws;
  unsigned short* YA = (unsigned short*)w;               // 51,200,000 B
  unsigned char*  Bi = (unsigned char*)(w + 51200000);   // 12,800,000
  unsigned char*  Bt = (unsigned char*)(w + 64000000);   // 12,800,000
  int* cnt_i = (int*)(w + 76800000);                     //  1,600,000 (8 x 50000)
  int* cnt_t = (int*)(w + 78400000);                     //  1,600,000 (contiguous)
  unsigned short* so_i = (unsigned short*)(w + 80000000);  // 12,800,000 (u16, 128/node)
  unsigned short* so_t = (unsigned short*)(w + 92800000);  // 12,800,000
  unsigned short* wtf = (unsigned short*)(w + 105600000); //    524,288  -> 106.1 MB total

  k_prep0<<<1024 + 391, 256, 0, stream>>>(W_int, W_tp, wtf, cnt_i);
  // 1271 blocks = 97*13 + 10: per 13 -> 8 gemm + 5 scatter (gemm 782, scatter 487)
  k_fused<<<dim3(1271), dim3(256), 0, stream>>>(x, wtf, b_int, b_tp, YA, Bi, Bt, NN,
                                                e_int, e_tp, cnt_i, cnt_t, so_i, so_t);
  k_agg2<<<12500, 256, 0, stream>>>(YA, (const uint32_t*)Bi, (const uint32_t*)Bt,
                                    cnt_i, cnt_t, (const uint32_t*)so_i, (const uint32_t*)so_t, out);
}